// Round 1
// baseline (8171.837 us; speedup 1.0000x reference)
//
#include <hip/hip_runtime.h>
#include <math.h>

#define HID 256
#define NGRAPH 64

// ---------------- SGEMM: C[M,N] = A[M,K] @ B[K,N], fp32, row-major ----------------
#define BMT 128
#define BNT 128
#define BKT 8
#define TM 8
#define TN 8

__global__ __launch_bounds__(256) void sgemm_kernel(
    const float* __restrict__ A, const float* __restrict__ Bm, float* __restrict__ C,
    int M, int N, int K) {
  __shared__ float As[BKT][BMT];
  __shared__ float Bs[BKT][BNT];
  const int tid = threadIdx.x;
  const int m0 = blockIdx.y * BMT;
  const int n0 = blockIdx.x * BNT;

  const int arow = tid >> 1;          // 0..127
  const int acol = (tid & 1) * 4;     // 0 or 4
  const int brow = tid >> 5;          // 0..7
  const int bcol = (tid & 31) * 4;    // 0..124
  const int tm = (tid >> 4) * TM;     // 0..120
  const int tn = (tid & 15) * TN;     // 0..120

  float acc[TM][TN];
#pragma unroll
  for (int i = 0; i < TM; ++i)
#pragma unroll
    for (int j = 0; j < TN; ++j) acc[i][j] = 0.f;

  const bool kvec = ((K & 3) == 0);   // K=771 rows are not 16B aligned -> scalar path
  const int ktiles = (K + BKT - 1) / BKT;
  for (int kt = 0; kt < ktiles; ++kt) {
    const int k0 = kt * BKT;
    {  // A tile -> As (transposed)
      const int gm = m0 + arow;
      const int gk = k0 + acol;
      float4 v = make_float4(0.f, 0.f, 0.f, 0.f);
      if (gm < M) {
        const float* p = A + (size_t)gm * K + gk;
        if (kvec && gk + 4 <= K) {
          v = *(const float4*)p;
        } else {
          if (gk + 0 < K) v.x = p[0];
          if (gk + 1 < K) v.y = p[1];
          if (gk + 2 < K) v.z = p[2];
          if (gk + 3 < K) v.w = p[3];
        }
      }
      As[acol + 0][arow] = v.x;
      As[acol + 1][arow] = v.y;
      As[acol + 2][arow] = v.z;
      As[acol + 3][arow] = v.w;
    }
    {  // B tile (weights: N multiple of 4 -> aligned float4)
      const int gk = k0 + brow;
      float4 v = make_float4(0.f, 0.f, 0.f, 0.f);
      if (gk < K) v = *(const float4*)(Bm + (size_t)gk * N + n0 + bcol);
      *(float4*)&Bs[brow][bcol] = v;
    }
    __syncthreads();
#pragma unroll
    for (int k = 0; k < BKT; ++k) {
      float ar[TM], br[TN];
      const float4* a4 = (const float4*)&As[k][tm];
      ((float4*)ar)[0] = a4[0];
      ((float4*)ar)[1] = a4[1];
      const float4* b4 = (const float4*)&Bs[k][tn];
      ((float4*)br)[0] = b4[0];
      ((float4*)br)[1] = b4[1];
#pragma unroll
      for (int i = 0; i < TM; ++i)
#pragma unroll
        for (int j = 0; j < TN; ++j) acc[i][j] = fmaf(ar[i], br[j], acc[i][j]);
    }
    __syncthreads();
  }
#pragma unroll
  for (int i = 0; i < TM; ++i) {
    const int gm = m0 + tm + i;
    if (gm < M) {
      float* cp = C + (size_t)gm * N + n0 + tn;
      *(float4*)cp = make_float4(acc[i][0], acc[i][1], acc[i][2], acc[i][3]);
      *(float4*)(cp + 4) = make_float4(acc[i][4], acc[i][5], acc[i][6], acc[i][7]);
    }
  }
}

// ---------------- degree ----------------
__global__ void deg_kernel(const int* __restrict__ dst, float* __restrict__ deg, int nE) {
  int e = blockIdx.x * blockDim.x + threadIdx.x;
  if (e < nE) atomicAdd(&deg[dst[e]], 1.0f);
}

// ---------------- edge scatter-add in HID dim: one wave per edge ----------------
__global__ __launch_bounds__(256) void scatter_kernel(
    const float* __restrict__ hl, const int* __restrict__ src, const int* __restrict__ dst,
    float* __restrict__ msum, int nE) {
  const int wid = (blockIdx.x * blockDim.x + threadIdx.x) >> 6;
  const int lane = threadIdx.x & 63;
  if (wid >= nE) return;
  const int s = src[wid];
  const int d = dst[wid];
  const float4 v = ((const float4*)(hl + (size_t)s * HID))[lane];
  float* o = msum + (size_t)d * HID + lane * 4;
  atomicAdd(o + 0, v.x);
  atomicAdd(o + 1, v.y);
  atomicAdd(o + 2, v.z);
  atomicAdd(o + 3, v.w);
}

// ---------------- preBN = msum/maxdeg + bl + hr ; accumulate channel sum/sumsq ----------------
#define CROWS 512
__global__ __launch_bounds__(256) void combine_stats_kernel(
    const float* __restrict__ msum, const float* __restrict__ hr, const float* __restrict__ deg,
    const float* __restrict__ bl, float* __restrict__ preBN,
    float* __restrict__ bsum, float* __restrict__ bsumsq, int M) {
  const int c = threadIdx.x;
  const int r0 = blockIdx.x * CROWS;
  const int r1 = min(r0 + CROWS, M);
  const float blc = bl[c];
  float s = 0.f, s2 = 0.f;
  for (int r = r0; r < r1; ++r) {
    const float rd = 1.0f / fmaxf(deg[r], 1.0f);
    const size_t idx = (size_t)r * HID + c;
    const float v = fmaf(msum[idx], rd, blc + hr[idx]);
    preBN[idx] = v;
    s += v;
    s2 = fmaf(v, v, s2);
  }
  atomicAdd(&bsum[c], s);
  atomicAdd(&bsumsq[c], s2);
}

__global__ void bn_finalize_kernel(const float* __restrict__ bsum, const float* __restrict__ bsumsq,
                                   const float* __restrict__ g, const float* __restrict__ b,
                                   float* __restrict__ scale, float* __restrict__ shift, int M) {
  const int c = threadIdx.x;
  const float inv = 1.0f / (float)M;
  const float mean = bsum[c] * inv;
  const float var = bsumsq[c] * inv - mean * mean;
  const float rstd = rsqrtf(var + 1e-5f);
  const float sc = g[c] * rstd;
  scale[c] = sc;
  shift[c] = b[c] - mean * sc;
}

__global__ __launch_bounds__(256) void bn_apply_relu_kernel(
    const float* __restrict__ preBN, const float* __restrict__ scale, const float* __restrict__ shift,
    float* __restrict__ hout, int n4) {
  const int i = blockIdx.x * blockDim.x + threadIdx.x;
  if (i >= n4) return;
  const int c4 = i & (HID / 4 - 1);
  const float4 v = ((const float4*)preBN)[i];
  const float4 sc = ((const float4*)scale)[c4];
  const float4 sh = ((const float4*)shift)[c4];
  float4 o;
  o.x = fmaxf(fmaf(v.x, sc.x, sh.x), 0.f);
  o.y = fmaxf(fmaf(v.y, sc.y, sh.y), 0.f);
  o.z = fmaxf(fmaf(v.z, sc.z, sh.z), 0.f);
  o.w = fmaxf(fmaf(v.w, sc.w, sh.w), 0.f);
  ((float4*)hout)[i] = o;
}

// ---------------- attention score: s = tanh(t + ba1) @ Wa2 + ba2, one wave per node ----------------
__global__ __launch_bounds__(256) void att_score_kernel(
    const float* __restrict__ t, const float* __restrict__ ba1, const float* __restrict__ Wa2,
    const float* __restrict__ ba2, float* __restrict__ s, int M) {
  const int wid = (blockIdx.x * blockDim.x + threadIdx.x) >> 6;
  const int lane = threadIdx.x & 63;
  if (wid >= M) return;
  const float* row = t + (size_t)wid * 128;
  float acc = tanhf(row[lane] + ba1[lane]) * Wa2[lane] +
              tanhf(row[lane + 64] + ba1[lane + 64]) * Wa2[lane + 64];
#pragma unroll
  for (int off = 32; off > 0; off >>= 1) acc += __shfl_down(acc, off, 64);
  if (lane == 0) s[wid] = acc + ba2[0];
}

// monotone float<->uint keys for atomicMax on floats (incl. negatives)
__device__ __forceinline__ unsigned fflip(float f) {
  unsigned u = __float_as_uint(f);
  return (u & 0x80000000u) ? ~u : (u | 0x80000000u);
}
__device__ __forceinline__ float funflip(unsigned u) {
  return __uint_as_float((u & 0x80000000u) ? (u ^ 0x80000000u) : ~u);
}

__global__ void seg_max_kernel(const float* __restrict__ s, const int* __restrict__ batch,
                               unsigned* __restrict__ gmax, int M) {
  __shared__ unsigned lmax[NGRAPH];
  if (threadIdx.x < NGRAPH) lmax[threadIdx.x] = 0u;
  __syncthreads();
  for (int i = blockIdx.x * blockDim.x + threadIdx.x; i < M; i += gridDim.x * blockDim.x)
    atomicMax(&lmax[batch[i]], fflip(s[i]));
  __syncthreads();
  if (threadIdx.x < NGRAPH && lmax[threadIdx.x] != 0u) atomicMax(&gmax[threadIdx.x], lmax[threadIdx.x]);
}

__global__ void seg_expsum_kernel(const float* __restrict__ s, const int* __restrict__ batch,
                                  const unsigned* __restrict__ gmax, float* __restrict__ e,
                                  float* __restrict__ denom, int M) {
  __shared__ float ld[NGRAPH];
  if (threadIdx.x < NGRAPH) ld[threadIdx.x] = 0.f;
  __syncthreads();
  for (int i = blockIdx.x * blockDim.x + threadIdx.x; i < M; i += gridDim.x * blockDim.x) {
    const int b = batch[i];
    const float v = expf(s[i] - funflip(gmax[b]));
    e[i] = v;
    atomicAdd(&ld[b], v);
  }
  __syncthreads();
  if (threadIdx.x < NGRAPH && ld[threadIdx.x] != 0.f) atomicAdd(&denom[threadIdx.x], ld[threadIdx.x]);
}

// ---------------- weighted pooling: one wave per node ----------------
__global__ __launch_bounds__(256) void pool_kernel(
    const float* __restrict__ h, const float* __restrict__ e, const float* __restrict__ denom,
    const int* __restrict__ batch, float* __restrict__ pooled, int M) {
  const int wid = (blockIdx.x * blockDim.x + threadIdx.x) >> 6;
  const int lane = threadIdx.x & 63;
  if (wid >= M) return;
  const int b = batch[wid];
  const float w = e[wid] / denom[b];
  const float4 v = ((const float4*)(h + (size_t)wid * HID))[lane];
  float* o = pooled + (size_t)b * HID + lane * 4;
  atomicAdd(o + 0, v.x * w);
  atomicAdd(o + 1, v.y * w);
  atomicAdd(o + 2, v.z * w);
  atomicAdd(o + 3, v.w * w);
}

// ---------------- classifier: out[g] = relu(pooled @ Wc1 + bc1) @ Wc2 + bc2 ----------------
__global__ __launch_bounds__(128) void classifier_kernel(
    const float* __restrict__ pooled, const float* __restrict__ Wc1, const float* __restrict__ bc1,
    const float* __restrict__ Wc2, const float* __restrict__ bc2, float* __restrict__ out) {
  __shared__ float red[128];
  const int g = blockIdx.x;
  const int j = threadIdx.x;
  float acc = bc1[j];
  const float* p = pooled + (size_t)g * HID;
  for (int c = 0; c < HID; ++c) acc = fmaf(p[c], Wc1[c * 128 + j], acc);
  red[j] = fmaxf(acc, 0.f) * Wc2[j];
  __syncthreads();
  for (int off = 64; off > 0; off >>= 1) {
    if (j < off) red[j] += red[j + off];
    __syncthreads();
  }
  if (j == 0) out[g] = red[0] + bc2[0];
}

extern "C" void kernel_launch(void* const* d_in, const int* in_sizes, int n_in,
                              void* d_out, int out_size, void* d_ws, size_t ws_size,
                              hipStream_t stream) {
  const float* x = (const float*)d_in[0];
  const int* edge = (const int*)d_in[1];
  const int* batch = (const int*)d_in[2];
  const int M = in_sizes[2];          // 100000 nodes
  const int nE = in_sizes[1] / 2;     // 400000 edges
  const int IN_DIM = in_sizes[0] / M; // 771
  const int* src = edge;
  const int* dst = edge + nE;

  const size_t MN = (size_t)M * HID;  // 25.6M floats
  float* ws = (float*)d_ws;
  // 3 big buffers (hl/hr/t reuse one) + small scratch: ~295 MB total
  float* bufL = ws;            // hl, then hr, then attention t
  float* bufM = bufL + MN;     // msum -> preBN (in place)
  float* bufH = bufM + MN;     // layer output h
  float* deg = bufH + MN;                 // M
  float* bsum = deg + M;                  // 256
  float* bsumsq = bsum + HID;             // 256
  float* scale = bsumsq + HID;            // 256
  float* shift = scale + HID;             // 256
  float* ssc = shift + HID;               // M
  float* ew = ssc + M;                    // M
  unsigned* gmax = (unsigned*)(ew + M);   // 64
  float* denom = (float*)(gmax + NGRAPH); // 64
  float* pooled = denom + NGRAPH;         // 64*256

  // degree (shared by all 3 layers) + zero attention/pool accumulators
  hipMemsetAsync(deg, 0, (size_t)M * sizeof(float), stream);
  deg_kernel<<<(nE + 255) / 256, 256, 0, stream>>>(dst, deg, nE);
  hipMemsetAsync(gmax, 0, (size_t)(NGRAPH * 2 + NGRAPH * HID) * 4, stream);

  const float* h_in = x;
  int K = IN_DIM;
  const int n4 = (int)(MN / 4);
  for (int l = 0; l < 3; ++l) {
    const float* Wl = (const float*)d_in[3 + l * 5 + 0];
    const float* bl = (const float*)d_in[3 + l * 5 + 1];
    const float* Wr = (const float*)d_in[3 + l * 5 + 2];
    const float* gg = (const float*)d_in[3 + l * 5 + 3];
    const float* bb = (const float*)d_in[3 + l * 5 + 4];

    dim3 grid(HID / BNT, (M + BMT - 1) / BMT);
    // hl = h @ Wl  (GEMM-then-aggregate: mean_agg(h)@Wl == mean_agg(h@Wl))
    sgemm_kernel<<<grid, 256, 0, stream>>>(h_in, Wl, bufL, M, HID, K);
    hipMemsetAsync(bufM, 0, MN * sizeof(float), stream);
    scatter_kernel<<<(nE * 64 + 255) / 256, 256, 0, stream>>>(bufL, src, dst, bufM, nE);
    // hr = h @ Wr (reuse bufL; scatter is done with it by stream order)
    sgemm_kernel<<<grid, 256, 0, stream>>>(h_in, Wr, bufL, M, HID, K);
    hipMemsetAsync(bsum, 0, HID * 2 * sizeof(float), stream);
    combine_stats_kernel<<<(M + CROWS - 1) / CROWS, 256, 0, stream>>>(
        bufM, bufL, deg, bl, bufM, bsum, bsumsq, M);
    bn_finalize_kernel<<<1, HID, 0, stream>>>(bsum, bsumsq, gg, bb, scale, shift, M);
    bn_apply_relu_kernel<<<(n4 + 255) / 256, 256, 0, stream>>>(bufM, scale, shift, bufH, n4);
    h_in = bufH;
    K = HID;
  }

  // attention pooling
  dim3 gridA(1, (M + BMT - 1) / BMT);
  sgemm_kernel<<<gridA, 256, 0, stream>>>(bufH, (const float*)d_in[18], bufL, M, 128, HID);
  att_score_kernel<<<(M * 64 + 255) / 256, 256, 0, stream>>>(
      bufL, (const float*)d_in[19], (const float*)d_in[20], (const float*)d_in[21], ssc, M);
  seg_max_kernel<<<512, 256, 0, stream>>>(ssc, batch, gmax, M);
  seg_expsum_kernel<<<512, 256, 0, stream>>>(ssc, batch, gmax, ew, denom, M);
  pool_kernel<<<(M * 64 + 255) / 256, 256, 0, stream>>>(bufH, ew, denom, batch, pooled, M);
  classifier_kernel<<<NGRAPH, 128, 0, stream>>>(
      pooled, (const float*)d_in[22], (const float*)d_in[23],
      (const float*)d_in[24], (const float*)d_in[25], (float*)d_out);
}

// Round 2
// 3155.640 us; speedup vs baseline: 2.5896x; 2.5896x over previous
//
#include <hip/hip_runtime.h>
#include <math.h>

#define HID 256
#define NGRAPH 64

// ---------------- SGEMM: C[M,N] = A[M,K] @ B[K,N], fp32, row-major ----------------
#define BMT 128
#define BNT 128
#define BKT 8
#define TM 8
#define TN 8

__global__ __launch_bounds__(256) void sgemm_kernel(
    const float* __restrict__ A, const float* __restrict__ Bm, float* __restrict__ C,
    int M, int N, int K) {
  __shared__ float As[BKT][BMT];
  __shared__ float Bs[BKT][BNT];
  const int tid = threadIdx.x;
  const int m0 = blockIdx.y * BMT;
  const int n0 = blockIdx.x * BNT;

  const int arow = tid >> 1;          // 0..127
  const int acol = (tid & 1) * 4;     // 0 or 4
  const int brow = tid >> 5;          // 0..7
  const int bcol = (tid & 31) * 4;    // 0..124
  const int tm = (tid >> 4) * TM;     // 0..120
  const int tn = (tid & 15) * TN;     // 0..120

  float acc[TM][TN];
#pragma unroll
  for (int i = 0; i < TM; ++i)
#pragma unroll
    for (int j = 0; j < TN; ++j) acc[i][j] = 0.f;

  const bool kvec = ((K & 3) == 0);   // K=771 rows are not 16B aligned -> scalar path
  const int ktiles = (K + BKT - 1) / BKT;
  for (int kt = 0; kt < ktiles; ++kt) {
    const int k0 = kt * BKT;
    {  // A tile -> As (transposed)
      const int gm = m0 + arow;
      const int gk = k0 + acol;
      float4 v = make_float4(0.f, 0.f, 0.f, 0.f);
      if (gm < M) {
        const float* p = A + (size_t)gm * K + gk;
        if (kvec && gk + 4 <= K) {
          v = *(const float4*)p;
        } else {
          if (gk + 0 < K) v.x = p[0];
          if (gk + 1 < K) v.y = p[1];
          if (gk + 2 < K) v.z = p[2];
          if (gk + 3 < K) v.w = p[3];
        }
      }
      As[acol + 0][arow] = v.x;
      As[acol + 1][arow] = v.y;
      As[acol + 2][arow] = v.z;
      As[acol + 3][arow] = v.w;
    }
    {  // B tile (weights: N multiple of 4 -> aligned float4)
      const int gk = k0 + brow;
      float4 v = make_float4(0.f, 0.f, 0.f, 0.f);
      if (gk < K) v = *(const float4*)(Bm + (size_t)gk * N + n0 + bcol);
      *(float4*)&Bs[brow][bcol] = v;
    }
    __syncthreads();
#pragma unroll
    for (int k = 0; k < BKT; ++k) {
      float ar[TM], br[TN];
      const float4* a4 = (const float4*)&As[k][tm];
      ((float4*)ar)[0] = a4[0];
      ((float4*)ar)[1] = a4[1];
      const float4* b4 = (const float4*)&Bs[k][tn];
      ((float4*)br)[0] = b4[0];
      ((float4*)br)[1] = b4[1];
#pragma unroll
      for (int i = 0; i < TM; ++i)
#pragma unroll
        for (int j = 0; j < TN; ++j) acc[i][j] = fmaf(ar[i], br[j], acc[i][j]);
    }
    __syncthreads();
  }
#pragma unroll
  for (int i = 0; i < TM; ++i) {
    const int gm = m0 + tm + i;
    if (gm < M) {
      float* cp = C + (size_t)gm * N + n0 + tn;
      *(float4*)cp = make_float4(acc[i][0], acc[i][1], acc[i][2], acc[i][3]);
      *(float4*)(cp + 4) = make_float4(acc[i][4], acc[i][5], acc[i][6], acc[i][7]);
    }
  }
}

// ---------------- CSR build ----------------
__global__ void deg_count_kernel(const int* __restrict__ dst, int* __restrict__ degi, int nE) {
  int e = blockIdx.x * blockDim.x + threadIdx.x;
  if (e < nE) atomicAdd(&degi[dst[e]], 1);
}

__global__ __launch_bounds__(1024) void scan_kernel(const int* __restrict__ degi,
                                                    int* __restrict__ rowptr, int M) {
  __shared__ int part[1024];
  const int t = threadIdx.x;
  const int chunk = (M + 1023) / 1024;
  const int b0 = min(t * chunk, M);
  const int b1 = min(b0 + chunk, M);
  int s = 0;
  for (int i = b0; i < b1; ++i) s += degi[i];
  part[t] = s;
  __syncthreads();
  for (int off = 1; off < 1024; off <<= 1) {
    int v = (t >= off) ? part[t - off] : 0;
    __syncthreads();
    part[t] += v;
    __syncthreads();
  }
  int ex = (t == 0) ? 0 : part[t - 1];
  for (int i = b0; i < b1; ++i) {
    rowptr[i] = ex;
    ex += degi[i];
  }
  if (t == 1023) rowptr[M] = part[1023];
}

__global__ void fill_kernel(const int* __restrict__ src, const int* __restrict__ dst,
                            int* __restrict__ fill, const int* __restrict__ rowptr,
                            int* __restrict__ csr_src, int nE) {
  int e = blockIdx.x * blockDim.x + threadIdx.x;
  if (e >= nE) return;
  const int d = dst[e];
  const int pos = rowptr[d] + atomicAdd(&fill[d], 1);
  csr_src[pos] = src[e];
}

// ---------------- fused gather-mean + bias + hr + BN stats ----------------
// one wave per node; block = 4 waves handles GNB consecutive nodes
#define GNB 64
__global__ __launch_bounds__(256) void gather_combine_kernel(
    const float* __restrict__ hl, const float* hr,
    const int* __restrict__ rowptr, const int* __restrict__ csr_src,
    const float* __restrict__ bl, float* preBN,
    float* __restrict__ bsum, float* __restrict__ bsumsq, int M) {
  __shared__ float lsum[4][HID];
  __shared__ float lsq[4][HID];
  const int w = threadIdx.x >> 6;
  const int lane = threadIdx.x & 63;
  const float4 blv = ((const float4*)bl)[lane];
  float4 s = make_float4(0.f, 0.f, 0.f, 0.f);
  float4 q = make_float4(0.f, 0.f, 0.f, 0.f);
  const int base = blockIdx.x * GNB;
  for (int it = 0; it < GNB / 4; ++it) {
    const int n = base + it * 4 + w;
    if (n < M) {
      const int e0 = rowptr[n], e1 = rowptr[n + 1];
      float4 acc = make_float4(0.f, 0.f, 0.f, 0.f);
      for (int e = e0; e < e1; ++e) {
        const int sn = csr_src[e];
        const float4 v = ((const float4*)(hl + (size_t)sn * HID))[lane];
        acc.x += v.x; acc.y += v.y; acc.z += v.z; acc.w += v.w;
      }
      const float rd = 1.0f / fmaxf((float)(e1 - e0), 1.0f);
      const float4 hv = ((const float4*)(hr + (size_t)n * HID))[lane];
      float4 o;
      o.x = fmaf(acc.x, rd, blv.x + hv.x);
      o.y = fmaf(acc.y, rd, blv.y + hv.y);
      o.z = fmaf(acc.z, rd, blv.z + hv.z);
      o.w = fmaf(acc.w, rd, blv.w + hv.w);
      ((float4*)(preBN + (size_t)n * HID))[lane] = o;
      s.x += o.x; s.y += o.y; s.z += o.z; s.w += o.w;
      q.x = fmaf(o.x, o.x, q.x); q.y = fmaf(o.y, o.y, q.y);
      q.z = fmaf(o.z, o.z, q.z); q.w = fmaf(o.w, o.w, q.w);
    }
  }
  *(float4*)&lsum[w][lane * 4] = s;
  *(float4*)&lsq[w][lane * 4] = q;
  __syncthreads();
  const int c = threadIdx.x;
  const float ts = lsum[0][c] + lsum[1][c] + lsum[2][c] + lsum[3][c];
  const float tq = lsq[0][c] + lsq[1][c] + lsq[2][c] + lsq[3][c];
  atomicAdd(&bsum[c], ts);
  atomicAdd(&bsumsq[c], tq);
}

__global__ void bn_finalize_kernel(const float* __restrict__ bsum, const float* __restrict__ bsumsq,
                                   const float* __restrict__ g, const float* __restrict__ b,
                                   float* __restrict__ scale, float* __restrict__ shift, int M) {
  const int c = threadIdx.x;
  const float inv = 1.0f / (float)M;
  const float mean = bsum[c] * inv;
  const float var = bsumsq[c] * inv - mean * mean;
  const float rstd = rsqrtf(var + 1e-5f);
  const float sc = g[c] * rstd;
  scale[c] = sc;
  shift[c] = b[c] - mean * sc;
}

__global__ __launch_bounds__(256) void bn_apply_relu_kernel(
    const float* __restrict__ preBN, const float* __restrict__ scale, const float* __restrict__ shift,
    float* __restrict__ hout, int n4) {
  const int i = blockIdx.x * blockDim.x + threadIdx.x;
  if (i >= n4) return;
  const int c4 = i & (HID / 4 - 1);
  const float4 v = ((const float4*)preBN)[i];
  const float4 sc = ((const float4*)scale)[c4];
  const float4 sh = ((const float4*)shift)[c4];
  float4 o;
  o.x = fmaxf(fmaf(v.x, sc.x, sh.x), 0.f);
  o.y = fmaxf(fmaf(v.y, sc.y, sh.y), 0.f);
  o.z = fmaxf(fmaf(v.z, sc.z, sh.z), 0.f);
  o.w = fmaxf(fmaf(v.w, sc.w, sh.w), 0.f);
  ((float4*)hout)[i] = o;
}

// ---------------- attention score: s = tanh(t + ba1) @ Wa2 + ba2, one wave per node ----------------
__global__ __launch_bounds__(256) void att_score_kernel(
    const float* __restrict__ t, const float* __restrict__ ba1, const float* __restrict__ Wa2,
    const float* __restrict__ ba2, float* __restrict__ s, int M) {
  const int wid = (blockIdx.x * blockDim.x + threadIdx.x) >> 6;
  const int lane = threadIdx.x & 63;
  if (wid >= M) return;
  const float* row = t + (size_t)wid * 128;
  float acc = tanhf(row[lane] + ba1[lane]) * Wa2[lane] +
              tanhf(row[lane + 64] + ba1[lane + 64]) * Wa2[lane + 64];
#pragma unroll
  for (int off = 32; off > 0; off >>= 1) acc += __shfl_down(acc, off, 64);
  if (lane == 0) s[wid] = acc + ba2[0];
}

// monotone float<->uint keys for atomicMax on floats (incl. negatives)
__device__ __forceinline__ unsigned fflip(float f) {
  unsigned u = __float_as_uint(f);
  return (u & 0x80000000u) ? ~u : (u | 0x80000000u);
}
__device__ __forceinline__ float funflip(unsigned u) {
  return __uint_as_float((u & 0x80000000u) ? (u ^ 0x80000000u) : ~u);
}

__global__ void seg_max_kernel(const float* __restrict__ s, const int* __restrict__ batch,
                               unsigned* __restrict__ gmax, int M) {
  __shared__ unsigned lmax[NGRAPH];
  if (threadIdx.x < NGRAPH) lmax[threadIdx.x] = 0u;
  __syncthreads();
  for (int i = blockIdx.x * blockDim.x + threadIdx.x; i < M; i += gridDim.x * blockDim.x)
    atomicMax(&lmax[batch[i]], fflip(s[i]));
  __syncthreads();
  if (threadIdx.x < NGRAPH && lmax[threadIdx.x] != 0u) atomicMax(&gmax[threadIdx.x], lmax[threadIdx.x]);
}

__global__ void seg_expsum_kernel(const float* __restrict__ s, const int* __restrict__ batch,
                                  const unsigned* __restrict__ gmax, float* __restrict__ e,
                                  float* __restrict__ denom, int M) {
  __shared__ float ld[NGRAPH];
  if (threadIdx.x < NGRAPH) ld[threadIdx.x] = 0.f;
  __syncthreads();
  for (int i = blockIdx.x * blockDim.x + threadIdx.x; i < M; i += gridDim.x * blockDim.x) {
    const int b = batch[i];
    const float v = expf(s[i] - funflip(gmax[b]));
    e[i] = v;
    atomicAdd(&ld[b], v);
  }
  __syncthreads();
  if (threadIdx.x < NGRAPH && ld[threadIdx.x] != 0.f) atomicAdd(&denom[threadIdx.x], ld[threadIdx.x]);
}

// ---------------- weighted pooling: one wave per PNB consecutive nodes ----------------
// batch is sorted -> register-accumulate per graph run, flush on change (16x fewer atomics)
#define PNB 16
__global__ __launch_bounds__(256) void pool_kernel(
    const float* __restrict__ h, const float* __restrict__ e, const float* __restrict__ denom,
    const int* __restrict__ batch, float* __restrict__ pooled, int M) {
  const int wid = (blockIdx.x * blockDim.x + threadIdx.x) >> 6;
  const int lane = threadIdx.x & 63;
  const int n0 = wid * PNB;
  if (n0 >= M) return;
  const int n1 = min(n0 + PNB, M);
  float4 acc = make_float4(0.f, 0.f, 0.f, 0.f);
  int cur = batch[n0];
  for (int n = n0; n < n1; ++n) {
    const int b = batch[n];
    if (b != cur) {
      float* o = pooled + (size_t)cur * HID + lane * 4;
      atomicAdd(o + 0, acc.x); atomicAdd(o + 1, acc.y);
      atomicAdd(o + 2, acc.z); atomicAdd(o + 3, acc.w);
      acc = make_float4(0.f, 0.f, 0.f, 0.f);
      cur = b;
    }
    const float w = e[n] / denom[b];
    const float4 v = ((const float4*)(h + (size_t)n * HID))[lane];
    acc.x = fmaf(v.x, w, acc.x); acc.y = fmaf(v.y, w, acc.y);
    acc.z = fmaf(v.z, w, acc.z); acc.w = fmaf(v.w, w, acc.w);
  }
  float* o = pooled + (size_t)cur * HID + lane * 4;
  atomicAdd(o + 0, acc.x); atomicAdd(o + 1, acc.y);
  atomicAdd(o + 2, acc.z); atomicAdd(o + 3, acc.w);
}

// ---------------- classifier: out[g] = relu(pooled @ Wc1 + bc1) @ Wc2 + bc2 ----------------
__global__ __launch_bounds__(128) void classifier_kernel(
    const float* __restrict__ pooled, const float* __restrict__ Wc1, const float* __restrict__ bc1,
    const float* __restrict__ Wc2, const float* __restrict__ bc2, float* __restrict__ out) {
  __shared__ float red[128];
  const int g = blockIdx.x;
  const int j = threadIdx.x;
  float acc = bc1[j];
  const float* p = pooled + (size_t)g * HID;
  for (int c = 0; c < HID; ++c) acc = fmaf(p[c], Wc1[c * 128 + j], acc);
  red[j] = fmaxf(acc, 0.f) * Wc2[j];
  __syncthreads();
  for (int off = 64; off > 0; off >>= 1) {
    if (j < off) red[j] += red[j + off];
    __syncthreads();
  }
  if (j == 0) out[g] = red[0] + bc2[0];
}

extern "C" void kernel_launch(void* const* d_in, const int* in_sizes, int n_in,
                              void* d_out, int out_size, void* d_ws, size_t ws_size,
                              hipStream_t stream) {
  const float* x = (const float*)d_in[0];
  const int* edge = (const int*)d_in[1];
  const int* batch = (const int*)d_in[2];
  const int M = in_sizes[2];          // 100000 nodes
  const int nE = in_sizes[1] / 2;     // 400000 edges
  const int IN_DIM = in_sizes[0] / M; // 771
  const int* src = edge;
  const int* dst = edge + nE;

  const size_t MN = (size_t)M * HID;  // 25.6M floats
  float* ws = (float*)d_ws;
  float* buf[3];
  buf[0] = ws;            // A
  buf[1] = ws + MN;       // B
  buf[2] = ws + 2 * MN;   // C
  float* small = ws + 3 * MN;
  float* bsum = small;                    // 256
  float* bsumsq = bsum + HID;             // 256
  float* scale = bsumsq + HID;            // 256
  float* shift = scale + HID;             // 256
  float* ssc = shift + HID;               // M
  float* ew = ssc + M;                    // M
  unsigned* gmax = (unsigned*)(ew + M);   // 64
  float* denom = (float*)(gmax + NGRAPH); // 64
  float* pooled = denom + NGRAPH;         // 64*256
  int* degi = (int*)(pooled + (size_t)NGRAPH * HID);  // M
  int* filla = degi + M;                              // M (adjacent to degi for one memset)
  int* rowptr = filla + M;                            // M+1
  int* csr_src = rowptr + M + 1;                      // nE

  // ---- CSR build (per call; ws is re-poisoned before every launch) ----
  hipMemsetAsync(degi, 0, (size_t)(2 * M) * sizeof(int), stream);  // degi + filla
  deg_count_kernel<<<(nE + 255) / 256, 256, 0, stream>>>(dst, degi, nE);
  scan_kernel<<<1, 1024, 0, stream>>>(degi, rowptr, M);
  fill_kernel<<<(nE + 255) / 256, 256, 0, stream>>>(src, dst, filla, rowptr, csr_src, nE);
  // zero attention/pool accumulators (gmax, denom, pooled contiguous)
  hipMemsetAsync(gmax, 0, (size_t)(NGRAPH * 2 + NGRAPH * HID) * 4, stream);

  const float* h_in = x;
  int K = IN_DIM;
  const int n4 = (int)(MN / 4);
  for (int l = 0; l < 3; ++l) {
    const float* Wl = (const float*)d_in[3 + l * 5 + 0];
    const float* bl = (const float*)d_in[3 + l * 5 + 1];
    const float* Wr = (const float*)d_in[3 + l * 5 + 2];
    const float* gg = (const float*)d_in[3 + l * 5 + 3];
    const float* bb = (const float*)d_in[3 + l * 5 + 4];

    float* gl = buf[l % 3];        // hl
    float* gr = buf[(l + 1) % 3];  // hr
    float* pb = buf[(l + 2) % 3];  // preBN (dead buffer / old h_in, free after GEMMs)
    float* ho = gl;                // layer output overwrites hl (dead after gather)

    dim3 grid(HID / BNT, (M + BMT - 1) / BMT);
    sgemm_kernel<<<grid, 256, 0, stream>>>(h_in, Wl, gl, M, HID, K);
    sgemm_kernel<<<grid, 256, 0, stream>>>(h_in, Wr, gr, M, HID, K);
    hipMemsetAsync(bsum, 0, HID * 2 * sizeof(float), stream);
    gather_combine_kernel<<<(M + GNB - 1) / GNB, 256, 0, stream>>>(
        gl, gr, rowptr, csr_src, bl, pb, bsum, bsumsq, M);
    bn_finalize_kernel<<<1, HID, 0, stream>>>(bsum, bsumsq, gg, bb, scale, shift, M);
    bn_apply_relu_kernel<<<(n4 + 255) / 256, 256, 0, stream>>>(pb, scale, shift, ho, n4);
    h_in = ho;
    K = HID;
  }
  // final h lives in buf[2] (l=2: ho = buf[2])
  const float* h = h_in;
  float* tbuf = buf[0];  // free now

  // attention pooling
  dim3 gridA(1, (M + BMT - 1) / BMT);
  sgemm_kernel<<<gridA, 256, 0, stream>>>(h, (const float*)d_in[18], tbuf, M, 128, HID);
  att_score_kernel<<<(M * 64 + 255) / 256, 256, 0, stream>>>(
      tbuf, (const float*)d_in[19], (const float*)d_in[20], (const float*)d_in[21], ssc, M);
  seg_max_kernel<<<512, 256, 0, stream>>>(ssc, batch, gmax, M);
  seg_expsum_kernel<<<512, 256, 0, stream>>>(ssc, batch, gmax, ew, denom, M);
  {
    const int nwaves = (M + PNB - 1) / PNB;
    pool_kernel<<<(nwaves * 64 + 255) / 256, 256, 0, stream>>>(h, ew, denom, batch, pooled, M);
  }
  classifier_kernel<<<NGRAPH, 128, 0, stream>>>(
      pooled, (const float*)d_in[22], (const float*)d_in[23],
      (const float*)d_in[24], (const float*)d_in[25], (float*)d_out);
}

// Round 3
// 2143.394 us; speedup vs baseline: 3.8126x; 1.4723x over previous
//
#include <hip/hip_runtime.h>
#include <math.h>
#include <stdint.h>

#define HID 256
#define NGRAPH 64
typedef unsigned short ushort_t;

typedef __attribute__((ext_vector_type(8))) short short8;
typedef __attribute__((ext_vector_type(4))) float f32x4;

// exact fp32 -> bf16 hi/lo split (RNE both)
__device__ __forceinline__ void split2(float v, ushort_t& h, ushort_t& l) {
  unsigned u = __float_as_uint(v);
  unsigned hr = u + 0x7FFFu + ((u >> 16) & 1u);
  h = (ushort_t)(hr >> 16);
  float hf = __uint_as_float(((unsigned)h) << 16);
  float r = v - hf;
  unsigned u2 = __float_as_uint(r);
  unsigned lr = u2 + 0x7FFFu + ((u2 >> 16) & 1u);
  l = (ushort_t)(lr >> 16);
}

#define GLDS(g, l) \
  __builtin_amdgcn_global_load_lds((const __attribute__((address_space(1))) void*)(g), \
                                   (__attribute__((address_space(3))) void*)(l), 16, 0, 0)

// ---------------- MFMA split-bf16 GEMM ----------------
// C[M,N] fp32 += ... actually writes: C = Ahi*Bhi + Ahi*Blo + Alo*Bhi
// A: [Mpad][Kpad] bf16 (hi,lo), B: [N][Kpad] bf16 (transposed weights)
__global__ __launch_bounds__(256) void mfma_gemm_kernel(
    const ushort_t* __restrict__ Ah, const ushort_t* __restrict__ Al,
    const ushort_t* __restrict__ Bh, const ushort_t* __restrict__ Bl,
    float* __restrict__ C, int Mrows, int N, int Kpad) {
  __shared__ ushort_t lAh[128 * 32];
  __shared__ ushort_t lAl[128 * 32];
  __shared__ ushort_t lBh[128 * 32];
  __shared__ ushort_t lBl[128 * 32];
  const int tid = threadIdx.x;
  const int m0 = blockIdx.y * 128;
  const int n0 = blockIdx.x * 128;
  const int w = tid >> 6, lane = tid & 63;
  const int wm = (w >> 1) * 64, wn = (w & 1) * 64;
  const int col = lane & 15, quad = lane >> 4;

  f32x4 acc[4][4];
#pragma unroll
  for (int i = 0; i < 4; ++i)
#pragma unroll
    for (int j = 0; j < 4; ++j) acc[i][j] = (f32x4)(0.f);

  for (int kt = 0; kt < Kpad; kt += 32) {
#pragma unroll
    for (int j = 0; j < 2; ++j) {
      const int ch = tid + j * 256;
      const int r = ch >> 2, c = ch & 3;
      const size_t goA = (size_t)(m0 + r) * Kpad + kt + c * 8;
      const size_t goB = (size_t)(n0 + r) * Kpad + kt + c * 8;
      GLDS(Ah + goA, &lAh[ch * 8]);
      GLDS(Al + goA, &lAl[ch * 8]);
      GLDS(Bh + goB, &lBh[ch * 8]);
      GLDS(Bl + goB, &lBl[ch * 8]);
    }
    __syncthreads();
    short8 ah[4], al[4], bh[4], bl[4];
#pragma unroll
    for (int i = 0; i < 4; ++i) {
      const int ar = wm + i * 16 + col;
      ah[i] = *(const short8*)&lAh[ar * 32 + quad * 8];
      al[i] = *(const short8*)&lAl[ar * 32 + quad * 8];
      const int br = wn + i * 16 + col;
      bh[i] = *(const short8*)&lBh[br * 32 + quad * 8];
      bl[i] = *(const short8*)&lBl[br * 32 + quad * 8];
    }
    __syncthreads();
#pragma unroll
    for (int i = 0; i < 4; ++i)
#pragma unroll
      for (int j = 0; j < 4; ++j) {
        acc[i][j] = __builtin_amdgcn_mfma_f32_16x16x32_bf16(ah[i], bh[j], acc[i][j], 0, 0, 0);
        acc[i][j] = __builtin_amdgcn_mfma_f32_16x16x32_bf16(ah[i], bl[j], acc[i][j], 0, 0, 0);
        acc[i][j] = __builtin_amdgcn_mfma_f32_16x16x32_bf16(al[i], bh[j], acc[i][j], 0, 0, 0);
      }
  }
#pragma unroll
  for (int i = 0; i < 4; ++i) {
    const int r0 = m0 + wm + i * 16 + quad * 4;
#pragma unroll
    for (int j = 0; j < 4; ++j) {
      const int cc = n0 + wn + j * 16 + col;
#pragma unroll
      for (int r = 0; r < 4; ++r)
        if (r0 + r < Mrows) C[(size_t)(r0 + r) * N + cc] = acc[i][j][r];
    }
  }
}

// ---------------- conversions ----------------
// x rows [row0, row0+nrows) of [*, K] fp32 -> [nrows][Kpad] bf16 hi/lo (zero pad)
__global__ __launch_bounds__(256) void convert_x_kernel(
    const float* __restrict__ x, int row0, int nrows,
    ushort_t* __restrict__ xh, ushort_t* __restrict__ xl, int K, int Kpad) {
  const int perRow = Kpad / 4;
  const int t = blockIdx.x * blockDim.x + threadIdx.x;
  if (t >= nrows * perRow) return;
  const int r = t / perRow, k0 = (t % perRow) * 4;
  const float* xr = x + (size_t)(row0 + r) * K;
  ushort_t h[4], l[4];
#pragma unroll
  for (int i = 0; i < 4; ++i) {
    const float v = (k0 + i < K) ? xr[k0 + i] : 0.f;
    split2(v, h[i], l[i]);
  }
  const size_t o = (size_t)r * Kpad + k0;
  *(ushort4*)(xh + o) = make_ushort4(h[0], h[1], h[2], h[3]);
  *(ushort4*)(xl + o) = make_ushort4(l[0], l[1], l[2], l[3]);
}

// W [K][N] fp32 -> WT [N][Kpad] bf16 hi/lo (zero pad)
__global__ void convert_wt_kernel(const float* __restrict__ W, ushort_t* __restrict__ wth,
                                  ushort_t* __restrict__ wtl, int K, int N, int Kpad) {
  const int t = blockIdx.x * blockDim.x + threadIdx.x;
  if (t >= N * Kpad) return;
  const int n = t / Kpad, k = t % Kpad;
  const float v = (k < K) ? W[(size_t)k * N + n] : 0.f;
  ushort_t h, l;
  split2(v, h, l);
  wth[t] = h;
  wtl[t] = l;
}

// ---------------- CSR build ----------------
__global__ void deg_count_kernel(const int* __restrict__ dst, int* __restrict__ degi, int nE) {
  int e = blockIdx.x * blockDim.x + threadIdx.x;
  if (e < nE) atomicAdd(&degi[dst[e]], 1);
}

__global__ __launch_bounds__(1024) void scan_kernel(const int* __restrict__ degi,
                                                    int* __restrict__ rowptr, int M) {
  __shared__ int part[1024];
  const int t = threadIdx.x;
  const int chunk = (M + 1023) / 1024;
  const int b0 = min(t * chunk, M);
  const int b1 = min(b0 + chunk, M);
  int s = 0;
  for (int i = b0; i < b1; ++i) s += degi[i];
  part[t] = s;
  __syncthreads();
  for (int off = 1; off < 1024; off <<= 1) {
    int v = (t >= off) ? part[t - off] : 0;
    __syncthreads();
    part[t] += v;
    __syncthreads();
  }
  int ex = (t == 0) ? 0 : part[t - 1];
  for (int i = b0; i < b1; ++i) {
    rowptr[i] = ex;
    ex += degi[i];
  }
  if (t == 1023) rowptr[M] = part[1023];
}

__global__ void fill_kernel(const int* __restrict__ src, const int* __restrict__ dst,
                            int* __restrict__ fill, const int* __restrict__ rowptr,
                            int* __restrict__ csr_src, int nE) {
  int e = blockIdx.x * blockDim.x + threadIdx.x;
  if (e >= nE) return;
  const int d = dst[e];
  const int pos = rowptr[d] + atomicAdd(&fill[d], 1);
  csr_src[pos] = src[e];
}

// ---------------- fused gather-mean + bias + hr + BN stats ----------------
#define GNB 64
__global__ __launch_bounds__(256) void gather_combine_kernel(
    const float* __restrict__ hl, const float* hr,
    const int* __restrict__ rowptr, const int* __restrict__ csr_src,
    const float* __restrict__ bl, float* preBN,
    float* __restrict__ bsum, float* __restrict__ bsumsq, int M) {
  __shared__ float lsum[4][HID];
  __shared__ float lsq[4][HID];
  const int w = threadIdx.x >> 6;
  const int lane = threadIdx.x & 63;
  const float4 blv = ((const float4*)bl)[lane];
  float4 s = make_float4(0.f, 0.f, 0.f, 0.f);
  float4 q = make_float4(0.f, 0.f, 0.f, 0.f);
  const int base = blockIdx.x * GNB;
  for (int it = 0; it < GNB / 4; ++it) {
    const int n = base + it * 4 + w;
    if (n < M) {
      const int e0 = rowptr[n], e1 = rowptr[n + 1];
      float4 acc = make_float4(0.f, 0.f, 0.f, 0.f);
      for (int e = e0; e < e1; ++e) {
        const int sn = csr_src[e];
        const float4 v = ((const float4*)(hl + (size_t)sn * HID))[lane];
        acc.x += v.x; acc.y += v.y; acc.z += v.z; acc.w += v.w;
      }
      const float rd = 1.0f / fmaxf((float)(e1 - e0), 1.0f);
      const float4 hv = ((const float4*)(hr + (size_t)n * HID))[lane];
      float4 o;
      o.x = fmaf(acc.x, rd, blv.x + hv.x);
      o.y = fmaf(acc.y, rd, blv.y + hv.y);
      o.z = fmaf(acc.z, rd, blv.z + hv.z);
      o.w = fmaf(acc.w, rd, blv.w + hv.w);
      ((float4*)(preBN + (size_t)n * HID))[lane] = o;
      s.x += o.x; s.y += o.y; s.z += o.z; s.w += o.w;
      q.x = fmaf(o.x, o.x, q.x); q.y = fmaf(o.y, o.y, q.y);
      q.z = fmaf(o.z, o.z, q.z); q.w = fmaf(o.w, o.w, q.w);
    }
  }
  *(float4*)&lsum[w][lane * 4] = s;
  *(float4*)&lsq[w][lane * 4] = q;
  __syncthreads();
  const int c = threadIdx.x;
  const float ts = lsum[0][c] + lsum[1][c] + lsum[2][c] + lsum[3][c];
  const float tq = lsq[0][c] + lsq[1][c] + lsq[2][c] + lsq[3][c];
  atomicAdd(&bsum[c], ts);
  atomicAdd(&bsumsq[c], tq);
}

__global__ void bn_finalize_kernel(const float* __restrict__ bsum, const float* __restrict__ bsumsq,
                                   const float* __restrict__ g, const float* __restrict__ b,
                                   float* __restrict__ scale, float* __restrict__ shift, int M) {
  const int c = threadIdx.x;
  const float inv = 1.0f / (float)M;
  const float mean = bsum[c] * inv;
  const float var = bsumsq[c] * inv - mean * mean;
  const float rstd = rsqrtf(var + 1e-5f);
  const float sc = g[c] * rstd;
  scale[c] = sc;
  shift[c] = b[c] - mean * sc;
}

// BN + ReLU, emit bf16 hi/lo split (and optional fp32 copy for the last layer)
__global__ __launch_bounds__(256) void bn_apply_relu_convert_kernel(
    const float* __restrict__ preBN, const float* __restrict__ scale, const float* __restrict__ shift,
    ushort_t* __restrict__ hh, ushort_t* __restrict__ hl, float* __restrict__ hout, int n4) {
  const int i = blockIdx.x * blockDim.x + threadIdx.x;
  if (i >= n4) return;
  const int c4 = i & (HID / 4 - 1);
  const float4 v = ((const float4*)preBN)[i];
  const float4 sc = ((const float4*)scale)[c4];
  const float4 sh = ((const float4*)shift)[c4];
  float o[4];
  o[0] = fmaxf(fmaf(v.x, sc.x, sh.x), 0.f);
  o[1] = fmaxf(fmaf(v.y, sc.y, sh.y), 0.f);
  o[2] = fmaxf(fmaf(v.z, sc.z, sh.z), 0.f);
  o[3] = fmaxf(fmaf(v.w, sc.w, sh.w), 0.f);
  ushort_t h[4], l[4];
#pragma unroll
  for (int k = 0; k < 4; ++k) split2(o[k], h[k], l[k]);
  ((ushort4*)hh)[i] = make_ushort4(h[0], h[1], h[2], h[3]);
  ((ushort4*)hl)[i] = make_ushort4(l[0], l[1], l[2], l[3]);
  if (hout) ((float4*)hout)[i] = make_float4(o[0], o[1], o[2], o[3]);
}

// ---------------- attention score ----------------
__global__ __launch_bounds__(256) void att_score_kernel(
    const float* __restrict__ t, const float* __restrict__ ba1, const float* __restrict__ Wa2,
    const float* __restrict__ ba2, float* __restrict__ s, int M) {
  const int wid = (blockIdx.x * blockDim.x + threadIdx.x) >> 6;
  const int lane = threadIdx.x & 63;
  if (wid >= M) return;
  const float* row = t + (size_t)wid * 128;
  float acc = tanhf(row[lane] + ba1[lane]) * Wa2[lane] +
              tanhf(row[lane + 64] + ba1[lane + 64]) * Wa2[lane + 64];
#pragma unroll
  for (int off = 32; off > 0; off >>= 1) acc += __shfl_down(acc, off, 64);
  if (lane == 0) s[wid] = acc + ba2[0];
}

__device__ __forceinline__ unsigned fflip(float f) {
  unsigned u = __float_as_uint(f);
  return (u & 0x80000000u) ? ~u : (u | 0x80000000u);
}
__device__ __forceinline__ float funflip(unsigned u) {
  return __uint_as_float((u & 0x80000000u) ? (u ^ 0x80000000u) : ~u);
}

__global__ void seg_max_kernel(const float* __restrict__ s, const int* __restrict__ batch,
                               unsigned* __restrict__ gmax, int M) {
  __shared__ unsigned lmax[NGRAPH];
  if (threadIdx.x < NGRAPH) lmax[threadIdx.x] = 0u;
  __syncthreads();
  for (int i = blockIdx.x * blockDim.x + threadIdx.x; i < M; i += gridDim.x * blockDim.x)
    atomicMax(&lmax[batch[i]], fflip(s[i]));
  __syncthreads();
  if (threadIdx.x < NGRAPH && lmax[threadIdx.x] != 0u) atomicMax(&gmax[threadIdx.x], lmax[threadIdx.x]);
}

__global__ void seg_expsum_kernel(const float* __restrict__ s, const int* __restrict__ batch,
                                  const unsigned* __restrict__ gmax, float* __restrict__ e,
                                  float* __restrict__ denom, int M) {
  __shared__ float ld[NGRAPH];
  if (threadIdx.x < NGRAPH) ld[threadIdx.x] = 0.f;
  __syncthreads();
  for (int i = blockIdx.x * blockDim.x + threadIdx.x; i < M; i += gridDim.x * blockDim.x) {
    const int b = batch[i];
    const float v = expf(s[i] - funflip(gmax[b]));
    e[i] = v;
    atomicAdd(&ld[b], v);
  }
  __syncthreads();
  if (threadIdx.x < NGRAPH && ld[threadIdx.x] != 0.f) atomicAdd(&denom[threadIdx.x], ld[threadIdx.x]);
}

#define PNB 16
__global__ __launch_bounds__(256) void pool_kernel(
    const float* __restrict__ h, const float* __restrict__ e, const float* __restrict__ denom,
    const int* __restrict__ batch, float* __restrict__ pooled, int M) {
  const int wid = (blockIdx.x * blockDim.x + threadIdx.x) >> 6;
  const int lane = threadIdx.x & 63;
  const int n0 = wid * PNB;
  if (n0 >= M) return;
  const int n1 = min(n0 + PNB, M);
  float4 acc = make_float4(0.f, 0.f, 0.f, 0.f);
  int cur = batch[n0];
  for (int n = n0; n < n1; ++n) {
    const int b = batch[n];
    if (b != cur) {
      float* o = pooled + (size_t)cur * HID + lane * 4;
      atomicAdd(o + 0, acc.x); atomicAdd(o + 1, acc.y);
      atomicAdd(o + 2, acc.z); atomicAdd(o + 3, acc.w);
      acc = make_float4(0.f, 0.f, 0.f, 0.f);
      cur = b;
    }
    const float w = e[n] / denom[b];
    const float4 v = ((const float4*)(h + (size_t)n * HID))[lane];
    acc.x = fmaf(v.x, w, acc.x); acc.y = fmaf(v.y, w, acc.y);
    acc.z = fmaf(v.z, w, acc.z); acc.w = fmaf(v.w, w, acc.w);
  }
  float* o = pooled + (size_t)cur * HID + lane * 4;
  atomicAdd(o + 0, acc.x); atomicAdd(o + 1, acc.y);
  atomicAdd(o + 2, acc.z); atomicAdd(o + 3, acc.w);
}

__global__ __launch_bounds__(128) void classifier_kernel(
    const float* __restrict__ pooled, const float* __restrict__ Wc1, const float* __restrict__ bc1,
    const float* __restrict__ Wc2, const float* __restrict__ bc2, float* __restrict__ out) {
  __shared__ float red[128];
  const int g = blockIdx.x;
  const int j = threadIdx.x;
  float acc = bc1[j];
  const float* p = pooled + (size_t)g * HID;
  for (int c = 0; c < HID; ++c) acc = fmaf(p[c], Wc1[c * 128 + j], acc);
  red[j] = fmaxf(acc, 0.f) * Wc2[j];
  __syncthreads();
  for (int off = 64; off > 0; off >>= 1) {
    if (j < off) red[j] += red[j + off];
    __syncthreads();
  }
  if (j == 0) out[g] = red[0] + bc2[0];
}

extern "C" void kernel_launch(void* const* d_in, const int* in_sizes, int n_in,
                              void* d_out, int out_size, void* d_ws, size_t ws_size,
                              hipStream_t stream) {
  const float* x = (const float*)d_in[0];
  const int* edge = (const int*)d_in[1];
  const int* batch = (const int*)d_in[2];
  const int M = in_sizes[2];
  const int nE = in_sizes[1] / 2;
  const int IN_DIM = in_sizes[0] / M;  // 771
  const int* src = edge;
  const int* dst = edge + nE;

  const size_t MN = (size_t)M * HID;
  const int Mpad = ((M + 127) / 128) * 128;
  const int KP0 = ((IN_DIM + 31) / 32) * 32;  // 800
  const int Mc = 25088;                       // layer-0 M-chunk (multiple of 128)

  float* ws = (float*)d_ws;
  float* buf0 = ws;
  float* buf1 = buf0 + MN;
  float* buf2 = buf1 + MN;
  float* bsum = buf2 + MN;                 // 256
  float* bsumsq = bsum + HID;
  float* scale = bsumsq + HID;
  float* shift = scale + HID;
  float* ssc = shift + HID;                // M
  float* ew = ssc + M;                     // M
  unsigned* gmax = (unsigned*)(ew + M);    // 64
  float* denom = (float*)(gmax + NGRAPH);  // 64
  float* pooled = denom + NGRAPH;          // 64*256
  int* degi = (int*)(pooled + (size_t)NGRAPH * HID);  // M
  int* filla = degi + M;                              // M
  int* rowptr = filla + M;                            // M+1
  int* csr_src = rowptr + M + 1;                      // nE

  // transposed-split weight area (16B aligned)
  ushort_t* wp = (ushort_t*)(((uintptr_t)(csr_src + nE) + 15) & ~(uintptr_t)15);
  const size_t W0SZ = (size_t)HID * KP0;   // 256*800
  const size_t W1SZ = (size_t)HID * HID;   // 256*256
  const size_t WASZ = (size_t)128 * HID;   // 128*256
  ushort_t* wlh[3], *wll[3], *wrh[3], *wrl[3];
  ushort_t* p = wp;
  for (int l = 0; l < 3; ++l) {
    const size_t sz = (l == 0) ? W0SZ : W1SZ;
    wlh[l] = p; p += sz;
    wll[l] = p; p += sz;
    wrh[l] = p; p += sz;
    wrl[l] = p; p += sz;
  }
  ushort_t* wah = p; p += WASZ;
  ushort_t* wal = p; p += WASZ;
  // conversion area (x chunks for layer 0, h splits after)
  ushort_t* cvh = (ushort_t*)(((uintptr_t)p + 15) & ~(uintptr_t)15);
  size_t CONVHALF = (size_t)Mc * KP0;
  if ((size_t)Mpad * HID > CONVHALF) CONVHALF = (size_t)Mpad * HID;
  ushort_t* cvl = cvh + CONVHALF;

  // ---- CSR build ----
  hipMemsetAsync(degi, 0, (size_t)(2 * M) * sizeof(int), stream);
  deg_count_kernel<<<(nE + 255) / 256, 256, 0, stream>>>(dst, degi, nE);
  scan_kernel<<<1, 1024, 0, stream>>>(degi, rowptr, M);
  fill_kernel<<<(nE + 255) / 256, 256, 0, stream>>>(src, dst, filla, rowptr, csr_src, nE);
  hipMemsetAsync(gmax, 0, (size_t)(NGRAPH * 2 + NGRAPH * HID) * 4, stream);

  // ---- weight transpose + split (all up front) ----
  for (int l = 0; l < 3; ++l) {
    const int K = (l == 0) ? IN_DIM : HID;
    const int KP = (l == 0) ? KP0 : HID;
    const float* Wl = (const float*)d_in[3 + l * 5 + 0];
    const float* Wr = (const float*)d_in[3 + l * 5 + 2];
    const int nt = HID * KP;
    convert_wt_kernel<<<(nt + 255) / 256, 256, 0, stream>>>(Wl, wlh[l], wll[l], K, HID, KP);
    convert_wt_kernel<<<(nt + 255) / 256, 256, 0, stream>>>(Wr, wrh[l], wrl[l], K, HID, KP);
  }
  convert_wt_kernel<<<(128 * HID + 255) / 256, 256, 0, stream>>>(
      (const float*)d_in[18], wah, wal, HID, 128, HID);

  const int n4 = (int)(MN / 4);
  for (int l = 0; l < 3; ++l) {
    const float* bl = (const float*)d_in[3 + l * 5 + 1];
    const float* gg = (const float*)d_in[3 + l * 5 + 3];
    const float* bb = (const float*)d_in[3 + l * 5 + 4];
    float* gl = (l == 0) ? buf0 : (l == 1) ? buf1 : buf2;
    float* gr = (l == 0) ? buf1 : (l == 1) ? buf2 : buf0;
    float* pb = (l == 0) ? buf2 : (l == 1) ? buf0 : buf1;

    if (l == 0) {
      // chunked: convert x rows -> split, then 2 GEMMs per chunk
      for (int c0 = 0; c0 < M; c0 += Mc) {
        const int rows = min(Mc, M - c0);
        const int nt = rows * (KP0 / 4);
        convert_x_kernel<<<(nt + 255) / 256, 256, 0, stream>>>(x, c0, rows, cvh, cvl, IN_DIM, KP0);
        dim3 g(HID / 128, (rows + 127) / 128);
        mfma_gemm_kernel<<<g, 256, 0, stream>>>(cvh, cvl, wlh[0], wll[0],
                                                gl + (size_t)c0 * HID, rows, HID, KP0);
        mfma_gemm_kernel<<<g, 256, 0, stream>>>(cvh, cvl, wrh[0], wrl[0],
                                                gr + (size_t)c0 * HID, rows, HID, KP0);
      }
    } else {
      dim3 g(HID / 128, (M + 127) / 128);
      mfma_gemm_kernel<<<g, 256, 0, stream>>>(cvh, cvl, wlh[l], wll[l], gl, M, HID, HID);
      mfma_gemm_kernel<<<g, 256, 0, stream>>>(cvh, cvl, wrh[l], wrl[l], gr, M, HID, HID);
    }
    hipMemsetAsync(bsum, 0, HID * 2 * sizeof(float), stream);
    gather_combine_kernel<<<(M + GNB - 1) / GNB, 256, 0, stream>>>(
        gl, gr, rowptr, csr_src, bl, pb, bsum, bsumsq, M);
    bn_finalize_kernel<<<1, HID, 0, stream>>>(bsum, bsumsq, gg, bb, scale, shift, M);
    // emit next-layer bf16 split; layer 2 also writes fp32 h (into gl, dead now)
    bn_apply_relu_convert_kernel<<<(n4 + 255) / 256, 256, 0, stream>>>(
        pb, scale, shift, cvh, cvl, (l == 2) ? gl : nullptr, n4);
  }
  const float* h = buf2;   // fp32 h of layer 2 (gl of l=2)
  float* tbuf = buf0;      // free

  // attention pooling (MFMA GEMM: t = h @ Wa1, N=128)
  {
    dim3 g(1, (M + 127) / 128);
    mfma_gemm_kernel<<<g, 256, 0, stream>>>(cvh, cvl, wah, wal, tbuf, M, 128, HID);
  }
  att_score_kernel<<<(M * 64 + 255) / 256, 256, 0, stream>>>(
      tbuf, (const float*)d_in[19], (const float*)d_in[20], (const float*)d_in[21], ssc, M);
  seg_max_kernel<<<512, 256, 0, stream>>>(ssc, batch, gmax, M);
  seg_expsum_kernel<<<512, 256, 0, stream>>>(ssc, batch, gmax, ew, denom, M);
  {
    const int nwaves = (M + PNB - 1) / PNB;
    pool_kernel<<<(nwaves * 64 + 255) / 256, 256, 0, stream>>>(h, ew, denom, batch, pooled, M);
  }
  classifier_kernel<<<NGRAPH, 128, 0, stream>>>(
      pooled, (const float*)d_in[22], (const float*)d_in[23],
      (const float*)d_in[24], (const float*)d_in[25], (float*)d_out);
}

// Round 5
// 2100.370 us; speedup vs baseline: 3.8907x; 1.0205x over previous
//
#include <hip/hip_runtime.h>
#include <math.h>
#include <stdint.h>

#define HID 256
#define NGRAPH 64
typedef unsigned short ushort_t;

typedef __attribute__((ext_vector_type(8))) short short8;
typedef __attribute__((ext_vector_type(4))) float f32x4;

// exact fp32 -> bf16 hi/lo split (RNE both)
__device__ __forceinline__ void split2(float v, ushort_t& h, ushort_t& l) {
  unsigned u = __float_as_uint(v);
  unsigned hr = u + 0x7FFFu + ((u >> 16) & 1u);
  h = (ushort_t)(hr >> 16);
  float hf = __uint_as_float(((unsigned)h) << 16);
  float r = v - hf;
  unsigned u2 = __float_as_uint(r);
  unsigned lr = u2 + 0x7FFFu + ((u2 >> 16) & 1u);
  l = (ushort_t)(lr >> 16);
}

#define GLDS(g, l) \
  __builtin_amdgcn_global_load_lds((const __attribute__((address_space(1))) void*)(g), \
                                   (__attribute__((address_space(3))) void*)(l), 16, 0, 0)

// ---------------- MFMA split-bf16 GEMM, fused N=512 ----------------
// A: [Mpad][Kpad] bf16 hi/lo. B: [512][Kpad] bf16 hi/lo (Wl^T rows 0-255, Wr^T 256-511).
// C: [M][512] fp32 = A*B^T (3-term split: hh + hl + lh)
__global__ __launch_bounds__(256) void mfma_gemm512_kernel(
    const ushort_t* __restrict__ Ah, const ushort_t* __restrict__ Al,
    const ushort_t* __restrict__ Bh, const ushort_t* __restrict__ Bl,
    float* __restrict__ C, int Mrows, int Kpad) {
  __shared__ ushort_t lAh[128 * 32];
  __shared__ ushort_t lAl[128 * 32];
  __shared__ ushort_t lBh[128 * 32];
  __shared__ ushort_t lBl[128 * 32];
  const int tid = threadIdx.x;
  const int m0 = blockIdx.y * 128;
  const int n0 = blockIdx.x * 128;
  const int w = tid >> 6, lane = tid & 63;
  const int wm = (w >> 1) * 64, wn = (w & 1) * 64;
  const int col = lane & 15, quad = lane >> 4;

  f32x4 acc[4][4];
#pragma unroll
  for (int i = 0; i < 4; ++i)
#pragma unroll
    for (int j = 0; j < 4; ++j) acc[i][j] = (f32x4)(0.f);

  for (int kt = 0; kt < Kpad; kt += 32) {
#pragma unroll
    for (int j = 0; j < 2; ++j) {
      const int ch = tid + j * 256;
      const int r = ch >> 2, c = ch & 3;
      const size_t goA = (size_t)(m0 + r) * Kpad + kt + c * 8;
      const size_t goB = (size_t)(n0 + r) * Kpad + kt + c * 8;
      GLDS(Ah + goA, &lAh[ch * 8]);
      GLDS(Al + goA, &lAl[ch * 8]);
      GLDS(Bh + goB, &lBh[ch * 8]);
      GLDS(Bl + goB, &lBl[ch * 8]);
    }
    __syncthreads();
    short8 ah[4], al[4], bh[4], bl[4];
#pragma unroll
    for (int i = 0; i < 4; ++i) {
      const int ar = wm + i * 16 + col;
      ah[i] = *(const short8*)&lAh[ar * 32 + quad * 8];
      al[i] = *(const short8*)&lAl[ar * 32 + quad * 8];
      const int br = wn + i * 16 + col;
      bh[i] = *(const short8*)&lBh[br * 32 + quad * 8];
      bl[i] = *(const short8*)&lBl[br * 32 + quad * 8];
    }
    __syncthreads();
#pragma unroll
    for (int i = 0; i < 4; ++i)
#pragma unroll
      for (int j = 0; j < 4; ++j) {
        acc[i][j] = __builtin_amdgcn_mfma_f32_16x16x32_bf16(ah[i], bh[j], acc[i][j], 0, 0, 0);
        acc[i][j] = __builtin_amdgcn_mfma_f32_16x16x32_bf16(ah[i], bl[j], acc[i][j], 0, 0, 0);
        acc[i][j] = __builtin_amdgcn_mfma_f32_16x16x32_bf16(al[i], bh[j], acc[i][j], 0, 0, 0);
      }
  }
#pragma unroll
  for (int i = 0; i < 4; ++i) {
    const int r0 = m0 + wm + i * 16 + quad * 4;
#pragma unroll
    for (int j = 0; j < 4; ++j) {
      const int cc = n0 + wn + j * 16 + col;
#pragma unroll
      for (int r = 0; r < 4; ++r)
        if (r0 + r < Mrows) C[(size_t)(r0 + r) * 512 + cc] = acc[i][j][r];
    }
  }
}

// ---------------- attention GEMM (N=128) with fused tanh-dot scorer ----------------
// computes t = h@Wa1 per 128x128 tile, then s[m] = sum_c tanh(t[m][c]+ba1[c])*Wa2[c] + ba2
__global__ __launch_bounds__(256) void mfma_att_kernel(
    const ushort_t* __restrict__ Ah, const ushort_t* __restrict__ Al,
    const ushort_t* __restrict__ Bh, const ushort_t* __restrict__ Bl,
    const float* __restrict__ ba1, const float* __restrict__ Wa2,
    const float* __restrict__ ba2, float* __restrict__ S, int Mrows, int Kpad) {
  __shared__ ushort_t lAh[128 * 32];
  __shared__ ushort_t lAl[128 * 32];
  __shared__ ushort_t lBh[128 * 32];
  __shared__ ushort_t lBl[128 * 32];
  __shared__ float sat[128][2];
  const int tid = threadIdx.x;
  const int m0 = blockIdx.y * 128;
  const int w = tid >> 6, lane = tid & 63;
  const int wm = (w >> 1) * 64, wn = (w & 1) * 64;
  const int col = lane & 15, quad = lane >> 4;

  f32x4 acc[4][4];
#pragma unroll
  for (int i = 0; i < 4; ++i)
#pragma unroll
    for (int j = 0; j < 4; ++j) acc[i][j] = (f32x4)(0.f);

  for (int kt = 0; kt < Kpad; kt += 32) {
#pragma unroll
    for (int j = 0; j < 2; ++j) {
      const int ch = tid + j * 256;
      const int r = ch >> 2, c = ch & 3;
      const size_t goA = (size_t)(m0 + r) * Kpad + kt + c * 8;
      const size_t goB = (size_t)r * Kpad + kt + c * 8;
      GLDS(Ah + goA, &lAh[ch * 8]);
      GLDS(Al + goA, &lAl[ch * 8]);
      GLDS(Bh + goB, &lBh[ch * 8]);
      GLDS(Bl + goB, &lBl[ch * 8]);
    }
    __syncthreads();
    short8 ah[4], al[4], bh[4], bl[4];
#pragma unroll
    for (int i = 0; i < 4; ++i) {
      const int ar = wm + i * 16 + col;
      ah[i] = *(const short8*)&lAh[ar * 32 + quad * 8];
      al[i] = *(const short8*)&lAl[ar * 32 + quad * 8];
      const int br = wn + i * 16 + col;
      bh[i] = *(const short8*)&lBh[br * 32 + quad * 8];
      bl[i] = *(const short8*)&lBl[br * 32 + quad * 8];
    }
    __syncthreads();
#pragma unroll
    for (int i = 0; i < 4; ++i)
#pragma unroll
      for (int j = 0; j < 4; ++j) {
        acc[i][j] = __builtin_amdgcn_mfma_f32_16x16x32_bf16(ah[i], bh[j], acc[i][j], 0, 0, 0);
        acc[i][j] = __builtin_amdgcn_mfma_f32_16x16x32_bf16(ah[i], bl[j], acc[i][j], 0, 0, 0);
        acc[i][j] = __builtin_amdgcn_mfma_f32_16x16x32_bf16(al[i], bh[j], acc[i][j], 0, 0, 0);
      }
  }
  // epilogue: per-row tanh-dot
  float part[4][4];
#pragma unroll
  for (int i = 0; i < 4; ++i)
#pragma unroll
    for (int r = 0; r < 4; ++r) part[i][r] = 0.f;
#pragma unroll
  for (int j = 0; j < 4; ++j) {
    const int cc = wn + j * 16 + col;
    const float a1 = ba1[cc];
    const float w2 = Wa2[cc];
#pragma unroll
    for (int i = 0; i < 4; ++i)
#pragma unroll
      for (int r = 0; r < 4; ++r)
        part[i][r] += tanhf(acc[i][j][r] + a1) * w2;
  }
#pragma unroll
  for (int mask = 1; mask < 16; mask <<= 1)
#pragma unroll
    for (int i = 0; i < 4; ++i)
#pragma unroll
      for (int r = 0; r < 4; ++r) part[i][r] += __shfl_xor(part[i][r], mask, 64);
  if (col == 0) {
#pragma unroll
    for (int i = 0; i < 4; ++i)
#pragma unroll
      for (int r = 0; r < 4; ++r) sat[wm + i * 16 + quad * 4 + r][wn >> 6] = part[i][r];
  }
  __syncthreads();
  if (tid < 128) {
    const int gm = m0 + tid;
    if (gm < Mrows) S[gm] = sat[tid][0] + sat[tid][1] + ba2[0];
  }
}

// ---------------- conversions ----------------
__global__ __launch_bounds__(256) void convert_x_kernel(
    const float* __restrict__ x, int nrows,
    ushort_t* __restrict__ xh, ushort_t* __restrict__ xl, int K, int Kpad) {
  const int perRow = Kpad / 4;
  const int t = blockIdx.x * blockDim.x + threadIdx.x;
  if (t >= nrows * perRow) return;
  const int r = t / perRow, k0 = (t % perRow) * 4;
  const float* xr = x + (size_t)r * K;
  ushort_t h[4], l[4];
#pragma unroll
  for (int i = 0; i < 4; ++i) {
    const float v = (k0 + i < K) ? xr[k0 + i] : 0.f;
    split2(v, h[i], l[i]);
  }
  const size_t o = (size_t)r * Kpad + k0;
  *(ushort4*)(xh + o) = make_ushort4(h[0], h[1], h[2], h[3]);
  *(ushort4*)(xl + o) = make_ushort4(l[0], l[1], l[2], l[3]);
}

// fused transpose+split: rows n<256 from W1[k][n], n>=256 from W2[k][n-256]
__global__ void convert_wt_kernel(const float* __restrict__ W1, const float* __restrict__ W2,
                                  ushort_t* __restrict__ wth, ushort_t* __restrict__ wtl,
                                  int K, int Kpad, int ntot, int ld) {
  const int t = blockIdx.x * blockDim.x + threadIdx.x;
  if (t >= ntot * Kpad) return;
  const int n = t / Kpad, k = t % Kpad;
  float v = 0.f;
  if (k < K) v = (n < 256) ? W1[(size_t)k * ld + n] : W2[(size_t)k * ld + (n - 256)];
  ushort_t h, l;
  split2(v, h, l);
  wth[t] = h;
  wtl[t] = l;
}

// ---------------- CSR build ----------------
__global__ void deg_count_kernel(const int* __restrict__ dst, int* __restrict__ degi, int nE) {
  int e = blockIdx.x * blockDim.x + threadIdx.x;
  if (e < nE) atomicAdd(&degi[dst[e]], 1);
}

__global__ __launch_bounds__(1024) void scan_kernel(const int* __restrict__ degi,
                                                    int* __restrict__ rowptr, int M) {
  __shared__ int part[1024];
  const int t = threadIdx.x;
  const int chunk = (M + 1023) / 1024;
  const int b0 = min(t * chunk, M);
  const int b1 = min(b0 + chunk, M);
  int s = 0;
  for (int i = b0; i < b1; ++i) s += degi[i];
  part[t] = s;
  __syncthreads();
  for (int off = 1; off < 1024; off <<= 1) {
    int v = (t >= off) ? part[t - off] : 0;
    __syncthreads();
    part[t] += v;
    __syncthreads();
  }
  int ex = (t == 0) ? 0 : part[t - 1];
  for (int i = b0; i < b1; ++i) {
    rowptr[i] = ex;
    ex += degi[i];
  }
  if (t == 1023) rowptr[M] = part[1023];
}

__global__ void fill_kernel(const int* __restrict__ src, const int* __restrict__ dst,
                            int* __restrict__ fill, const int* __restrict__ rowptr,
                            int* __restrict__ csr_src, int nE) {
  int e = blockIdx.x * blockDim.x + threadIdx.x;
  if (e >= nE) return;
  const int d = dst[e];
  const int pos = rowptr[d] + atomicAdd(&fill[d], 1);
  csr_src[pos] = src[e];
}

// ---------------- fused gather-mean + bias + hr + BN stats ----------------
// gbuf: [M][512] (cols 0-255 = hl, 256-511 = hr)
#define GNB 64
__global__ __launch_bounds__(256) void gather_combine_kernel(
    const float* __restrict__ gbuf,
    const int* __restrict__ rowptr, const int* __restrict__ csr_src,
    const float* __restrict__ bl, float* preBN,
    float* __restrict__ bsum, float* __restrict__ bsumsq, int M) {
  __shared__ float lsum[4][HID];
  __shared__ float lsq[4][HID];
  const int w = threadIdx.x >> 6;
  const int lane = threadIdx.x & 63;
  const float4 blv = ((const float4*)bl)[lane];
  float4 s = make_float4(0.f, 0.f, 0.f, 0.f);
  float4 q = make_float4(0.f, 0.f, 0.f, 0.f);
  const int base = blockIdx.x * GNB;
  for (int it = 0; it < GNB / 4; ++it) {
    const int n = base + it * 4 + w;
    if (n < M) {
      const int e0 = rowptr[n], e1 = rowptr[n + 1];
      float4 acc = make_float4(0.f, 0.f, 0.f, 0.f);
      for (int e = e0; e < e1; ++e) {
        const int sn = csr_src[e];
        const float4 v = ((const float4*)(gbuf + (size_t)sn * 512))[lane];
        acc.x += v.x; acc.y += v.y; acc.z += v.z; acc.w += v.w;
      }
      const float rd = 1.0f / fmaxf((float)(e1 - e0), 1.0f);
      const float4 hv = ((const float4*)(gbuf + (size_t)n * 512 + 256))[lane];
      float4 o;
      o.x = fmaf(acc.x, rd, blv.x + hv.x);
      o.y = fmaf(acc.y, rd, blv.y + hv.y);
      o.z = fmaf(acc.z, rd, blv.z + hv.z);
      o.w = fmaf(acc.w, rd, blv.w + hv.w);
      ((float4*)(preBN + (size_t)n * HID))[lane] = o;
      s.x += o.x; s.y += o.y; s.z += o.z; s.w += o.w;
      q.x = fmaf(o.x, o.x, q.x); q.y = fmaf(o.y, o.y, q.y);
      q.z = fmaf(o.z, o.z, q.z); q.w = fmaf(o.w, o.w, q.w);
    }
  }
  *(float4*)&lsum[w][lane * 4] = s;
  *(float4*)&lsq[w][lane * 4] = q;
  __syncthreads();
  const int c = threadIdx.x;
  const float ts = lsum[0][c] + lsum[1][c] + lsum[2][c] + lsum[3][c];
  const float tq = lsq[0][c] + lsq[1][c] + lsq[2][c] + lsq[3][c];
  atomicAdd(&bsum[c], ts);
  atomicAdd(&bsumsq[c], tq);
}

// BN(scale/shift recomputed per block) + ReLU -> bf16 split (+ optional fp32)
__global__ __launch_bounds__(256) void bn_apply_relu_convert_kernel(
    const float* __restrict__ preBN, const float* __restrict__ bsum,
    const float* __restrict__ bsumsq, const float* __restrict__ g, const float* __restrict__ b,
    ushort_t* __restrict__ hh, ushort_t* __restrict__ hl, float* __restrict__ hout,
    int M, int n4) {
  __shared__ float s_sc[HID], s_sh[HID];
  {
    const int c = threadIdx.x;
    const float inv = 1.0f / (float)M;
    const float mean = bsum[c] * inv;
    const float var = bsumsq[c] * inv - mean * mean;
    const float sc = g[c] * rsqrtf(var + 1e-5f);
    s_sc[c] = sc;
    s_sh[c] = b[c] - mean * sc;
  }
  __syncthreads();
  const int i = blockIdx.x * blockDim.x + threadIdx.x;
  if (i >= n4) return;
  const int c0 = (i & (HID / 4 - 1)) * 4;
  const float4 v = ((const float4*)preBN)[i];
  float o[4];
  o[0] = fmaxf(fmaf(v.x, s_sc[c0 + 0], s_sh[c0 + 0]), 0.f);
  o[1] = fmaxf(fmaf(v.y, s_sc[c0 + 1], s_sh[c0 + 1]), 0.f);
  o[2] = fmaxf(fmaf(v.z, s_sc[c0 + 2], s_sh[c0 + 2]), 0.f);
  o[3] = fmaxf(fmaf(v.w, s_sc[c0 + 3], s_sh[c0 + 3]), 0.f);
  ushort_t h[4], l[4];
#pragma unroll
  for (int k = 0; k < 4; ++k) split2(o[k], h[k], l[k]);
  ((ushort4*)hh)[i] = make_ushort4(h[0], h[1], h[2], h[3]);
  ((ushort4*)hl)[i] = make_ushort4(l[0], l[1], l[2], l[3]);
  if (hout) ((float4*)hout)[i] = make_float4(o[0], o[1], o[2], o[3]);
}

// ---------------- softmax over graphs ----------------
__device__ __forceinline__ unsigned fflip(float f) {
  unsigned u = __float_as_uint(f);
  return (u & 0x80000000u) ? ~u : (u | 0x80000000u);
}
__device__ __forceinline__ float funflip(unsigned u) {
  return __uint_as_float((u & 0x80000000u) ? (u ^ 0x80000000u) : ~u);
}

__global__ void seg_max_kernel(const float* __restrict__ s, const int* __restrict__ batch,
                               unsigned* __restrict__ gmax, int M) {
  __shared__ unsigned lmax[NGRAPH];
  if (threadIdx.x < NGRAPH) lmax[threadIdx.x] = 0u;
  __syncthreads();
  for (int i = blockIdx.x * blockDim.x + threadIdx.x; i < M; i += gridDim.x * blockDim.x)
    atomicMax(&lmax[batch[i]], fflip(s[i]));
  __syncthreads();
  if (threadIdx.x < NGRAPH && lmax[threadIdx.x] != 0u) atomicMax(&gmax[threadIdx.x], lmax[threadIdx.x]);
}

__global__ void seg_expsum_kernel(const float* __restrict__ s, const int* __restrict__ batch,
                                  const unsigned* __restrict__ gmax, float* __restrict__ e,
                                  float* __restrict__ denom, int M) {
  __shared__ float ld[NGRAPH];
  if (threadIdx.x < NGRAPH) ld[threadIdx.x] = 0.f;
  __syncthreads();
  for (int i = blockIdx.x * blockDim.x + threadIdx.x; i < M; i += gridDim.x * blockDim.x) {
    const int b = batch[i];
    const float v = expf(s[i] - funflip(gmax[b]));
    e[i] = v;
    atomicAdd(&ld[b], v);
  }
  __syncthreads();
  if (threadIdx.x < NGRAPH && ld[threadIdx.x] != 0.f) atomicAdd(&denom[threadIdx.x], ld[threadIdx.x]);
}

#define PNB 16
__global__ __launch_bounds__(256) void pool_kernel(
    const float* __restrict__ h, const float* __restrict__ e, const float* __restrict__ denom,
    const int* __restrict__ batch, float* __restrict__ pooled, int M) {
  const int wid = (blockIdx.x * blockDim.x + threadIdx.x) >> 6;
  const int lane = threadIdx.x & 63;
  const int n0 = wid * PNB;
  if (n0 >= M) return;
  const int n1 = min(n0 + PNB, M);
  float4 acc = make_float4(0.f, 0.f, 0.f, 0.f);
  int cur = batch[n0];
  for (int n = n0; n < n1; ++n) {
    const int b = batch[n];
    if (b != cur) {
      float* o = pooled + (size_t)cur * HID + lane * 4;
      atomicAdd(o + 0, acc.x); atomicAdd(o + 1, acc.y);
      atomicAdd(o + 2, acc.z); atomicAdd(o + 3, acc.w);
      acc = make_float4(0.f, 0.f, 0.f, 0.f);
      cur = b;
    }
    const float w = e[n] / denom[b];
    const float4 v = ((const float4*)(h + (size_t)n * HID))[lane];
    acc.x = fmaf(v.x, w, acc.x); acc.y = fmaf(v.y, w, acc.y);
    acc.z = fmaf(v.z, w, acc.z); acc.w = fmaf(v.w, w, acc.w);
  }
  float* o = pooled + (size_t)cur * HID + lane * 4;
  atomicAdd(o + 0, acc.x); atomicAdd(o + 1, acc.y);
  atomicAdd(o + 2, acc.z); atomicAdd(o + 3, acc.w);
}

__global__ __launch_bounds__(128) void classifier_kernel(
    const float* __restrict__ pooled, const float* __restrict__ Wc1, const float* __restrict__ bc1,
    const float* __restrict__ Wc2, const float* __restrict__ bc2, float* __restrict__ out) {
  __shared__ float red[128];
  const int g = blockIdx.x;
  const int j = threadIdx.x;
  float acc = bc1[j];
  const float* p = pooled + (size_t)g * HID;
  for (int c = 0; c < HID; ++c) acc = fmaf(p[c], Wc1[c * 128 + j], acc);
  red[j] = fmaxf(acc, 0.f) * Wc2[j];
  __syncthreads();
  for (int off = 64; off > 0; off >>= 1) {
    if (j < off) red[j] += red[j + off];
    __syncthreads();
  }
  if (j == 0) out[g] = red[0] + bc2[0];
}

extern "C" void kernel_launch(void* const* d_in, const int* in_sizes, int n_in,
                              void* d_out, int out_size, void* d_ws, size_t ws_size,
                              hipStream_t stream) {
  const float* x = (const float*)d_in[0];
  const int* edge = (const int*)d_in[1];
  const int* batch = (const int*)d_in[2];
  const int M = in_sizes[2];
  const int nE = in_sizes[1] / 2;
  const int IN_DIM = in_sizes[0] / M;  // 771
  const int* src = edge;
  const int* dst = edge + nE;

  const int Mpad = ((M + 127) / 128) * 128;
  const int KP0 = ((IN_DIM + 31) / 32) * 32;  // 800
  const int mblocks = (M + 127) / 128;

  float* ws = (float*)d_ws;
  float* gbuf = ws;                                    // [M][512]
  float* pbuf = gbuf + (size_t)M * 512;                // [M][256]
  float* h32 = pbuf + (size_t)M * HID;                 // [M][256]
  float* ssc = h32 + (size_t)M * HID;                  // M
  float* ew = ssc + M;                                 // M
  float* bsumA = ew + M;                               // 3 layers x (256 sum + 256 sq)
  unsigned* gmax = (unsigned*)(bsumA + 6 * HID);       // 64
  float* denom = (float*)(gmax + NGRAPH);              // 64
  float* pooled = denom + NGRAPH;                      // 64*256
  int* degi = (int*)(pooled + (size_t)NGRAPH * HID);   // M
  int* filla = degi + M;                               // M
  int* rowptr = filla + M;                             // M+1
  int* csr_src = rowptr + M + 1;                       // nE

  ushort_t* wp = (ushort_t*)(((uintptr_t)(csr_src + nE) + 15) & ~(uintptr_t)15);
  ushort_t* w0h = wp;                 ushort_t* w0l = w0h + (size_t)512 * KP0;
  ushort_t* w1h = w0l + (size_t)512 * KP0;  ushort_t* w1l = w1h + (size_t)512 * HID;
  ushort_t* w2h = w1l + (size_t)512 * HID;  ushort_t* w2l = w2h + (size_t)512 * HID;
  ushort_t* wah = w2l + (size_t)512 * HID;  ushort_t* wal = wah + (size_t)128 * HID;
  ushort_t* cvh = (ushort_t*)(((uintptr_t)(wal + (size_t)128 * HID) + 15) & ~(uintptr_t)15);
  ushort_t* cvl = cvh + (size_t)Mpad * KP0;

  // ---- CSR build ----
  hipMemsetAsync(degi, 0, (size_t)(2 * M) * sizeof(int), stream);
  deg_count_kernel<<<(nE + 255) / 256, 256, 0, stream>>>(dst, degi, nE);
  scan_kernel<<<1, 1024, 0, stream>>>(degi, rowptr, M);
  fill_kernel<<<(nE + 255) / 256, 256, 0, stream>>>(src, dst, filla, rowptr, csr_src, nE);
  // one memset for all small accumulators: bsumA(1536) + gmax(64) + denom(64) + pooled(16384)
  hipMemsetAsync(bsumA, 0, (size_t)(6 * HID + 2 * NGRAPH + NGRAPH * HID) * 4, stream);

  // ---- weight transpose + split (fused Wl||Wr per layer) ----
  {
    const int nt0 = 512 * KP0;
    convert_wt_kernel<<<(nt0 + 255) / 256, 256, 0, stream>>>(
        (const float*)d_in[3], (const float*)d_in[5], w0h, w0l, IN_DIM, KP0, 512, HID);
    const int nt1 = 512 * HID;
    convert_wt_kernel<<<(nt1 + 255) / 256, 256, 0, stream>>>(
        (const float*)d_in[8], (const float*)d_in[10], w1h, w1l, HID, HID, 512, HID);
    convert_wt_kernel<<<(nt1 + 255) / 256, 256, 0, stream>>>(
        (const float*)d_in[13], (const float*)d_in[15], w2h, w2l, HID, HID, 512, HID);
    convert_wt_kernel<<<(128 * HID + 255) / 256, 256, 0, stream>>>(
        (const float*)d_in[18], nullptr, wah, wal, HID, HID, 128, 128);
  }

  // layer-0 input split
  {
    const int nt = M * (KP0 / 4);
    convert_x_kernel<<<(nt + 255) / 256, 256, 0, stream>>>(x, M, cvh, cvl, IN_DIM, KP0);
  }

  const int n4 = (int)((size_t)M * HID / 4);
  const ushort_t* WH[3] = {w0h, w1h, w2h};
  const ushort_t* WL[3] = {w0l, w1l, w2l};
  for (int l = 0; l < 3; ++l) {
    const int KP = (l == 0) ? KP0 : HID;
    const float* bl = (const float*)d_in[3 + l * 5 + 1];
    const float* gg = (const float*)d_in[3 + l * 5 + 3];
    const float* bb = (const float*)d_in[3 + l * 5 + 4];
    float* bsum = bsumA + l * 512;
    float* bsumsq = bsum + HID;

    dim3 g(4, mblocks);
    mfma_gemm512_kernel<<<g, 256, 0, stream>>>(cvh, cvl, WH[l], WL[l], gbuf, M, KP);
    gather_combine_kernel<<<(M + GNB - 1) / GNB, 256, 0, stream>>>(
        gbuf, rowptr, csr_src, bl, pbuf, bsum, bsumsq, M);
    // overwrite cvh/cvl with next layer's split ([Mpad][256] fits in [Mpad][800] region)
    bn_apply_relu_convert_kernel<<<(n4 + 255) / 256, 256, 0, stream>>>(
        pbuf, bsum, bsumsq, gg, bb, cvh, cvl, (l == 2) ? h32 : nullptr, M, n4);
  }

  // attention scores (GEMM + fused tanh-dot epilogue)
  {
    dim3 g(1, mblocks);
    mfma_att_kernel<<<g, 256, 0, stream>>>(
        cvh, cvl, wah, wal, (const float*)d_in[19], (const float*)d_in[20],
        (const float*)d_in[21], ssc, M, HID);
  }
  seg_max_kernel<<<512, 256, 0, stream>>>(ssc, batch, gmax, M);
  seg_expsum_kernel<<<512, 256, 0, stream>>>(ssc, batch, gmax, ew, denom, M);
  {
    const int nwaves = (M + PNB - 1) / PNB;
    pool_kernel<<<(nwaves * 64 + 255) / 256, 256, 0, stream>>>(h32, ew, denom, batch, pooled, M);
  }
  classifier_kernel<<<NGRAPH, 128, 0, stream>>>(
      pooled, (const float*)d_in[22], (const float*)d_in[23],
      (const float*)d_in[24], (const float*)d_in[25], (float*)d_out);
}